// Round 6
// baseline (13157.887 us; speedup 1.0000x reference)
//
#include <hip/hip_runtime.h>
#include <hip/hip_bf16.h>
#include <math.h>

// Problem constants
#define A_DIM 1024      // NB_ATOMS
#define D_DIM 768       // 3*16*16
#define B_DIM 16384     // BATCH
#define TEMP_C 100.0f
#define EPS_C 1e-8f

// Round 6: the nondiff phase has ZERO GEMMs. State = gradient buffer G[B,A]:
//   c' = (1-lam_b) c + lam_b am   =>   g' = (1-lam_b) g + lam_b (S_b - q),
//   S_b[a'] = sum_{a: bstar[a]==b} X[a,a']  (row-gather of X, L2-resident).
// g0 = colsum(X)/1024 - q (uniform c0). Per-iter: initnd + stats (G lookups +
// pairs scan) + fused_update (one memory pass: updates C,G; computes c.g row
// sums and c.Xc) + argmin kernel. Diff phase: one 2-product MFMA GEMM per iter
// (A-operand = single bf16 hi; fine since no argmin downstream), first diff
// iter skips the GEMM (G already holds the gradient from the recurrence).
// Workspace ~196 MiB (same as round 5's proven size).

typedef __attribute__((ext_vector_type(8))) short short8;
typedef __attribute__((ext_vector_type(4))) float f32x4;
#define MFMA16(a, b, c) __builtin_amdgcn_mfma_f32_16x16x32_bf16(a, b, c, 0, 0, 0)

typedef __attribute__((address_space(3))) unsigned char lds_byte;
typedef __attribute__((address_space(1))) const unsigned char g_byte;
__device__ __forceinline__ void async_copy16(const void* gptr, void* lptr) {
    __builtin_amdgcn_global_load_lds((g_byte*)gptr, (lds_byte*)lptr, 16, 0, 0);
}

// ---------------- small helpers ----------------

__device__ __forceinline__ float block_reduce_sum(float v, float* red) {
    int t = threadIdx.x;
    red[t] = v; __syncthreads();
    for (int off = 128; off > 0; off >>= 1) {
        if (t < off) red[t] += red[t + off];
        __syncthreads();
    }
    float r = red[0];
    __syncthreads();
    return r;
}

__device__ __forceinline__ float block_reduce_max(float v, float* red) {
    int t = threadIdx.x;
    red[t] = v; __syncthreads();
    for (int off = 128; off > 0; off >>= 1) {
        if (t < off) red[t] = fmaxf(red[t], red[t + off]);
        __syncthreads();
    }
    float r = red[0];
    __syncthreads();
    return r;
}

// monotone float->uint transform for ordered integer min
__device__ __forceinline__ unsigned int fkey(float v) {
    unsigned int u = __float_as_uint(v);
    return u ^ ((u & 0x80000000u) ? 0xFFFFFFFFu : 0x80000000u);
}

// bf16 round-to-nearest-even + two-term split
__device__ __forceinline__ unsigned short f2bf(float x) {
    unsigned int u = __float_as_uint(x);
    return (unsigned short)((u + 0x7FFFu + ((u >> 16) & 1u)) >> 16);
}
__device__ __forceinline__ float bf2f(unsigned short h) {
    return __uint_as_float(((unsigned int)h) << 16);
}
__device__ __forceinline__ void split2(float x, unsigned short& hi, unsigned short& lo) {
    hi = f2bf(x);
    lo = f2bf(x - bf2f(hi));
}

// ---------------- MFMA building blocks ----------------

__device__ __forceinline__ void stage_tile8(const unsigned short* gsrc, int stride, int k0,
                                            unsigned short* ltile, int lane) {
    int srow = lane >> 2;
    int scol = (lane & 3) * 8;
#pragma unroll
    for (int s = 0; s < 8; s++) {
        const unsigned short* src = gsrc + (size_t)(s * 16 + srow) * stride + k0 + scol;
        async_copy16(src, ltile + s * 512);
    }
}

// 3-product (pair x pair) K=32 step — recon GEMM only
__device__ __forceinline__ void mfma_k32(const unsigned short* lds, int wm, int wn, int lane,
                                         f32x4 acc[4][4]) {
    int frow = lane & 15, fk = (lane >> 4) * 8;
    short8 ah[4], al[4], bh[4], bl[4];
#pragma unroll
    for (int t = 0; t < 4; t++) {
        int ar = (wm * 64 + t * 16 + frow) * 32 + fk;
        ah[t] = *(const short8*)&lds[ar];
        al[t] = *(const short8*)&lds[4096 + ar];
        int br = (wn * 64 + t * 16 + frow) * 32 + fk;
        bh[t] = *(const short8*)&lds[8192 + br];
        bl[t] = *(const short8*)&lds[12288 + br];
    }
#pragma unroll
    for (int i = 0; i < 4; i++)
#pragma unroll
        for (int j = 0; j < 4; j++) {
            acc[i][j] = MFMA16(ah[i], bh[j], acc[i][j]);
            acc[i][j] = MFMA16(ah[i], bl[j], acc[i][j]);
            acc[i][j] = MFMA16(al[i], bh[j], acc[i][j]);
        }
}

// 2-product (single-A x pair-B) K=32 step — diff-phase GEMMs
__device__ __forceinline__ void mfma_k32_2p(const unsigned short* lds, int wm, int wn, int lane,
                                            f32x4 acc[4][4]) {
    int frow = lane & 15, fk = (lane >> 4) * 8;
    short8 ah[4], bh[4], bl[4];
#pragma unroll
    for (int t = 0; t < 4; t++) {
        int ar = (wm * 64 + t * 16 + frow) * 32 + fk;
        ah[t] = *(const short8*)&lds[ar];
        int br = (wn * 64 + t * 16 + frow) * 32 + fk;
        bh[t] = *(const short8*)&lds[8192 + br];
        bl[t] = *(const short8*)&lds[12288 + br];
    }
#pragma unroll
    for (int i = 0; i < 4; i++)
#pragma unroll
        for (int j = 0; j < 4; j++) {
            acc[i][j] = MFMA16(ah[i], bh[j], acc[i][j]);
            acc[i][j] = MFMA16(ah[i], bl[j], acc[i][j]);
        }
}

// ---------------- setup kernels ----------------

__global__ __launch_bounds__(256) void ynorm_kernel(const float* __restrict__ y,
                                                    float* __restrict__ ynorm) {
    __shared__ float red[256];
    int b = blockIdx.x;
    const float* row = y + (size_t)b * D_DIM;
    float s = 0.f;
    for (int i = threadIdx.x; i < D_DIM; i += 256) s += fabsf(row[i]);
    float tot = block_reduce_sum(s, red);
    if (threadIdx.x == 0) ynorm[b] = tot;
}

__global__ __launch_bounds__(256) void anorm_kernel(const float* __restrict__ atoms,
                                                    float* __restrict__ an,
                                                    float* __restrict__ anrm) {
    __shared__ float red[256];
    int a = blockIdx.x;
    const float* row = atoms + (size_t)a * D_DIM;
    float s = 0.f;
    for (int i = threadIdx.x; i < D_DIM; i += 256) s += fabsf(row[i]);
    float tot = block_reduce_sum(s, red);
    float inv = 1.f / tot;
    float* orow = an + (size_t)a * D_DIM;
    for (int i = threadIdx.x; i < D_DIM; i += 256) orow[i] = row[i] * inv;
    if (threadIdx.x == 0) anrm[a] = tot;
}

__global__ __launch_bounds__(256) void atrans_split_kernel(const float* __restrict__ atoms,
                                                           const float* __restrict__ anrm,
                                                           unsigned short* __restrict__ AnTh,
                                                           unsigned short* __restrict__ AnTl) {
    int n = blockIdx.x;
    for (int k = threadIdx.x; k < A_DIM; k += 256) {
        float v = atoms[(size_t)k * D_DIM + n] / anrm[k];
        unsigned short h, l;
        split2(v, h, l);
        AnTh[(size_t)n * A_DIM + k] = h;
        AnTl[(size_t)n * A_DIM + k] = l;
    }
}

__global__ __launch_bounds__(256) void split_kernel(const float* __restrict__ src,
                                                    unsigned short* __restrict__ hi,
                                                    unsigned short* __restrict__ lo,
                                                    int n4) {
    int i = blockIdx.x * 256 + threadIdx.x;
    if (i < n4) {
        float4 v = ((const float4*)src)[i];
        ushort4 h, l;
        split2(v.x, h.x, l.x);
        split2(v.y, h.y, l.y);
        split2(v.z, h.z, l.z);
        split2(v.w, h.w, l.w);
        ((ushort4*)hi)[i] = h;
        ((ushort4*)lo)[i] = l;
    }
}

__global__ __launch_bounds__(256) void fill_pair_kernel(unsigned short* __restrict__ Chi,
                                                        unsigned short* __restrict__ Clo,
                                                        size_t n4) {
    size_t i = (size_t)blockIdx.x * 256 + threadIdx.x;
    if (i < n4) {
        unsigned short h, l;
        split2(1.f / A_DIM, h, l);
        ((ushort4*)Chi)[i] = make_ushort4(h, h, h, h);
        ((ushort4*)Clo)[i] = make_ushort4(l, l, l, l);
    }
}

// fp32 vector GEMM, B transposed ([N,K] row-major), setup only.
// EPI 0: plain (X = an@an^T). EPI 3: /rscale[row] (qt = y@an^T / ynorm).
template <int EPI>
__global__ __launch_bounds__(256) void gemm_bt(const float* __restrict__ Aop,
                                               const float* __restrict__ Bop,
                                               const float* __restrict__ rscale,
                                               float* __restrict__ Cout,
                                               int N, int K) {
    const int LDT = 132;
    __shared__ float As[16 * LDT];
    __shared__ float Bs[16 * LDT];
    int m0 = blockIdx.y * 128, n0 = blockIdx.x * 128;
    int tid = threadIdx.x;
    int tx = tid & 15, ty = tid >> 4;
    float acc[8][8];
#pragma unroll
    for (int i = 0; i < 8; i++)
#pragma unroll
        for (int j = 0; j < 8; j++) acc[i][j] = 0.f;
    for (int k0 = 0; k0 < K; k0 += 16) {
#pragma unroll
        for (int s = 0; s < 2; s++) {
            int idx = tid + s * 256;
            int row = idx >> 2, kq = (idx & 3) * 4;
            float4 v = *(const float4*)(Aop + (size_t)(m0 + row) * K + k0 + kq);
            As[(kq + 0) * LDT + row] = v.x;
            As[(kq + 1) * LDT + row] = v.y;
            As[(kq + 2) * LDT + row] = v.z;
            As[(kq + 3) * LDT + row] = v.w;
        }
#pragma unroll
        for (int s = 0; s < 2; s++) {
            int idx = tid + s * 256;
            int row = idx >> 2, kq = (idx & 3) * 4;
            float4 v = *(const float4*)(Bop + (size_t)(n0 + row) * K + k0 + kq);
            Bs[(kq + 0) * LDT + row] = v.x;
            Bs[(kq + 1) * LDT + row] = v.y;
            Bs[(kq + 2) * LDT + row] = v.z;
            Bs[(kq + 3) * LDT + row] = v.w;
        }
        __syncthreads();
#pragma unroll
        for (int kk = 0; kk < 16; kk++) {
            float a[8], b[8];
            *(float4*)(a)     = *(const float4*)(As + kk * LDT + ty * 8);
            *(float4*)(a + 4) = *(const float4*)(As + kk * LDT + ty * 8 + 4);
            *(float4*)(b)     = *(const float4*)(Bs + kk * LDT + tx * 8);
            *(float4*)(b + 4) = *(const float4*)(Bs + kk * LDT + tx * 8 + 4);
#pragma unroll
            for (int i = 0; i < 8; i++)
#pragma unroll
                for (int j = 0; j < 8; j++) acc[i][j] = fmaf(a[i], b[j], acc[i][j]);
        }
        __syncthreads();
    }
#pragma unroll
    for (int i = 0; i < 8; i++) {
        int row = m0 + ty * 8 + i;
        float rs = (EPI == 3) ? (1.f / rscale[row]) : 1.f;
#pragma unroll
        for (int j = 0; j < 8; j += 4) {
            int col = n0 + tx * 8 + j;
            float4 v = make_float4(acc[i][j] * rs, acc[i][j + 1] * rs,
                                   acc[i][j + 2] * rs, acc[i][j + 3] * rs);
            *(float4*)(Cout + (size_t)row * N + col) = v;
        }
    }
}

// cs[a] = sum_k Xrec[k,a]  (column sums; X symmetric so == row sums)
__global__ __launch_bounds__(256) void colsum_kernel(const unsigned short* __restrict__ Xhi,
                                                     const unsigned short* __restrict__ Xlo,
                                                     float* __restrict__ cs) {
    int a = blockIdx.x * 256 + threadIdx.x;
    float s = 0.f;
    for (int k = 0; k < A_DIM; k++)
        s += bf2f(Xhi[(size_t)k * A_DIM + a]) + bf2f(Xlo[(size_t)k * A_DIM + a]);
    cs[a] = s;
}

// G0 = cs/1024 - qt; num_cg[b] = c0.g0; s1cur += c0.(g0+q)
__global__ __launch_bounds__(256) void g0init_kernel(float* __restrict__ G,
                                                     const float* __restrict__ qt,
                                                     const float* __restrict__ cs,
                                                     float* __restrict__ num_cg,
                                                     float* __restrict__ s1cur) {
    __shared__ float red[256];
    int b = blockIdx.x;
    int i = threadIdx.x;
    const float c0 = 1.f / A_DIM;
    float4 q = ((const float4*)(qt + (size_t)b * A_DIM))[i];
    float4 c = ((const float4*)cs)[i];
    float4 g = make_float4(c.x * c0 - q.x, c.y * c0 - q.y, c.z * c0 - q.z, c.w * c0 - q.w);
    ((float4*)(G + (size_t)b * A_DIM))[i] = g;
    float ncg = c0 * (g.x + g.y + g.z + g.w);
    float s1 = c0 * c0 * (c.x + c.y + c.z + c.w);  // c0.(g+q) = c0.(cs*c0)
    float nt = block_reduce_sum(ncg, red);
    float st = block_reduce_sum(s1, red);
    if (i == 0) {
        num_cg[b] = nt;
        atomicAdd(s1cur, st);
    }
}

// ---------------- nondiff per-iteration kernels ----------------

__global__ __launch_bounds__(256) void init_pre_kernel(unsigned long long* __restrict__ keysA,
                                                       unsigned long long* __restrict__ keysB,
                                                       float* __restrict__ scal) {
    int i = blockIdx.x * 256 + threadIdx.x;
    if (i < A_DIM) { keysA[i] = ~0ULL; keysB[i] = ~0ULL; }
    if (i < 8) scal[i] = 0.f;
}

// reset next-bank keys, num_amg, scal0, scal2, s1next
__global__ __launch_bounds__(256) void initnd_kernel(unsigned long long* __restrict__ keys_next,
                                                     float* __restrict__ num_amg,
                                                     float* __restrict__ scal0,
                                                     float* __restrict__ scal2,
                                                     float* __restrict__ s1next) {
    int i = blockIdx.x * 256 + threadIdx.x;
    num_amg[i] = 0.f;
    if (i < A_DIM) keys_next[i] = ~0ULL;
    if (i == 0) { *scal0 = 0.f; *scal2 = 0.f; *s1next = 0.f; }
}

// column argmin over rows of G[B,A] into keys (packed fkey<<32 | row)
__global__ __launch_bounds__(256) void argmin_kernel(const float* __restrict__ G,
                                                     unsigned long long* __restrict__ keys) {
    __shared__ unsigned long long sk[256];
    int a0 = blockIdx.x * 64;
    int b0 = blockIdx.y * 1024;
    int c = threadIdx.x & 63;
    int r = threadIdx.x >> 6;
    float bestv = INFINITY;
    int bestb = 0;
    for (int b = b0 + r; b < b0 + 1024; b += 4) {
        float v = G[(size_t)b * A_DIM + a0 + c];
        if (v < bestv) { bestv = v; bestb = b; }
    }
    unsigned long long key = ((unsigned long long)fkey(bestv) << 32) | (unsigned int)bestb;
    sk[threadIdx.x] = key;
    __syncthreads();
    if (r == 0) {
        unsigned long long k = sk[c];
        k = min(k, sk[64 + c]);
        k = min(k, sk[128 + c]);
        k = min(k, sk[192 + c]);
        atomicMin(&keys[a0 + c], k);
    }
}

// block per atom a: bstar[a]; pairs scal0 += sum_{i:key==ba} Xrec[a,i];
// g lookup: num_amg[ba] += G[ba,a]; scal2 += G[ba,a] + qt[ba,a]
__global__ __launch_bounds__(256) void statsnd_kernel(const unsigned long long* __restrict__ keys,
                                                      const unsigned short* __restrict__ Xhi,
                                                      const unsigned short* __restrict__ Xlo,
                                                      const float* __restrict__ G,
                                                      const float* __restrict__ qt,
                                                      int* __restrict__ bstar,
                                                      float* __restrict__ num_amg,
                                                      float* __restrict__ scal0,
                                                      float* __restrict__ scal2) {
    __shared__ float red[256];
    int a = blockIdx.x;
    int ba = (int)(unsigned int)(keys[a] & 0xFFFFFFFFULL);
    const unsigned short* xh = Xhi + (size_t)a * A_DIM;
    const unsigned short* xl = Xlo + (size_t)a * A_DIM;
    float s = 0.f;
    for (int i = threadIdx.x; i < A_DIM; i += 256)
        if ((int)(unsigned int)(keys[i] & 0xFFFFFFFFULL) == ba)
            s += bf2f(xh[i]) + bf2f(xl[i]);
    float pt = block_reduce_sum(s, red);
    if (threadIdx.x == 0) {
        bstar[a] = ba;
        atomicAdd(scal0, pt);
        size_t idx = (size_t)ba * A_DIM + a;
        float gv = G[idx];
        atomicAdd(&num_amg[ba], gv);
        atomicAdd(scal2, gv + qt[idx]);
    }
}

// THE nondiff workhorse: one memory pass per iteration. Block per sample b.
//   lam_b = clip((num_cg[b]-num_amg[b]) / (scal0 + s1cur - 2*scal2 + eps))
//   S = gather of Xrec rows {a: bstar[a]==b}
//   G' = (1-lam) G + lam (S - q);  c' = (1-lam) c + lam am
//   num_cg[b] <- c'.G' ;  s1next += c'.(G'+q)
__global__ __launch_bounds__(256) void fused_update(unsigned short* __restrict__ Chi,
                                                    unsigned short* __restrict__ Clo,
                                                    float* __restrict__ G,
                                                    const float* __restrict__ qt,
                                                    const unsigned short* __restrict__ Xhi,
                                                    const unsigned short* __restrict__ Xlo,
                                                    const int* __restrict__ bstar,
                                                    float* __restrict__ num_cg,
                                                    const float* __restrict__ num_amg,
                                                    const float* __restrict__ scal0,
                                                    const float* __restrict__ s1cur,
                                                    const float* __restrict__ scal2,
                                                    float* __restrict__ s1next) {
    __shared__ int bs_l[1024];
    __shared__ int mlist[1024];
    __shared__ int mcount;
    __shared__ float red[256];
    int b = blockIdx.x;
    int t = threadIdx.x;
    if (t == 0) mcount = 0;
    __syncthreads();
    int4 bv = ((const int4*)bstar)[t];
    ((int4*)bs_l)[t] = bv;
    if (bv.x == b) mlist[atomicAdd(&mcount, 1)] = 4 * t + 0;
    if (bv.y == b) mlist[atomicAdd(&mcount, 1)] = 4 * t + 1;
    if (bv.z == b) mlist[atomicAdd(&mcount, 1)] = 4 * t + 2;
    if (bv.w == b) mlist[atomicAdd(&mcount, 1)] = 4 * t + 3;
    __syncthreads();
    int mc = mcount;

    float den = *scal0 + *s1cur - 2.f * *scal2 + EPS_C;
    float lam = fminf(fmaxf((num_cg[b] - num_amg[b]) / den, 0.f), 1.f);
    float om = 1.f - lam;

    float4 g = ((const float4*)(G + (size_t)b * A_DIM))[t];
    float4 q = ((const float4*)(qt + (size_t)b * A_DIM))[t];
    ushort4 h = ((const ushort4*)(Chi + (size_t)b * A_DIM))[t];
    ushort4 l = ((const ushort4*)(Clo + (size_t)b * A_DIM))[t];
    float c0 = bf2f(h.x) + bf2f(l.x);
    float c1 = bf2f(h.y) + bf2f(l.y);
    float c2 = bf2f(h.z) + bf2f(l.z);
    float c3 = bf2f(h.w) + bf2f(l.w);

    float S0 = 0.f, S1 = 0.f, S2 = 0.f, S3 = 0.f;
    for (int m = 0; m < mc; m++) {
        int a = mlist[m];
        ushort4 xh = ((const ushort4*)(Xhi + (size_t)a * A_DIM))[t];
        ushort4 xl = ((const ushort4*)(Xlo + (size_t)a * A_DIM))[t];
        S0 += bf2f(xh.x) + bf2f(xl.x);
        S1 += bf2f(xh.y) + bf2f(xl.y);
        S2 += bf2f(xh.z) + bf2f(xl.z);
        S3 += bf2f(xh.w) + bf2f(xl.w);
    }

    // new gradient
    g.x = om * g.x + lam * (S0 - q.x);
    g.y = om * g.y + lam * (S1 - q.y);
    g.z = om * g.z + lam * (S2 - q.z);
    g.w = om * g.w + lam * (S3 - q.w);
    ((float4*)(G + (size_t)b * A_DIM))[t] = g;

    // new c
    float a0 = (bs_l[4 * t + 0] == b) ? 1.f : 0.f;
    float a1 = (bs_l[4 * t + 1] == b) ? 1.f : 0.f;
    float a2 = (bs_l[4 * t + 2] == b) ? 1.f : 0.f;
    float a3 = (bs_l[4 * t + 3] == b) ? 1.f : 0.f;
    c0 = om * c0 + lam * a0;
    c1 = om * c1 + lam * a1;
    c2 = om * c2 + lam * a2;
    c3 = om * c3 + lam * a3;
    split2(c0, h.x, l.x);
    split2(c1, h.y, l.y);
    split2(c2, h.z, l.z);
    split2(c3, h.w, l.w);
    ((ushort4*)(Chi + (size_t)b * A_DIM))[t] = h;
    ((ushort4*)(Clo + (size_t)b * A_DIM))[t] = l;

    // next-iteration row stats
    float ncg = c0 * g.x + c1 * g.y + c2 * g.z + c3 * g.w;
    float s1 = c0 * (g.x + q.x) + c1 * (g.y + q.y) + c2 * (g.z + q.z) + c3 * (g.w + q.w);
    float nt = block_reduce_sum(ncg, red);
    float st = block_reduce_sum(s1, red);
    if (t == 0) {
        num_cg[b] = nt;
        atomicAdd(s1next, st);
    }
}

// ---------------- diff-phase GEMM (single-A x pair-X, 2 products) ----------------
// MODE 1: G[idx] = acc - qt[idx]          (A = c-hi)
// MODE 2: scal3 += sum(acc * recon(Chi,Clo))  (A = d-hi, dot for denominator)
template <int MODE>
__global__ __launch_bounds__(256) void gemm_single(const unsigned short* __restrict__ Ahi,
                                                   const unsigned short* __restrict__ Xhi,
                                                   const unsigned short* __restrict__ Xlo,
                                                   const float* __restrict__ qt,
                                                   const unsigned short* __restrict__ Chi,
                                                   const unsigned short* __restrict__ Clo,
                                                   float* __restrict__ G,
                                                   float* __restrict__ scal3) {
    __shared__ unsigned short lds[16384];
    __shared__ float red[256];
    int tid = threadIdx.x;
    int w = tid >> 6, lane = tid & 63;
    int wm = w >> 1, wn = w & 1;
    int m0 = blockIdx.y * 128, n0 = blockIdx.x * 128;

    f32x4 acc[4][4];
#pragma unroll
    for (int i = 0; i < 4; i++)
#pragma unroll
        for (int j = 0; j < 4; j++) acc[i][j] = f32x4{0.f, 0.f, 0.f, 0.f};

    const unsigned short* gsrc = nullptr;
    unsigned short* ltile = nullptr;
    if (w == 0) { gsrc = Ahi + (size_t)m0 * A_DIM; ltile = lds; }
    else if (w == 2) { gsrc = Xhi + (size_t)n0 * A_DIM; ltile = lds + 8192; }
    else if (w == 3) { gsrc = Xlo + (size_t)n0 * A_DIM; ltile = lds + 12288; }
    for (int k0 = 0; k0 < A_DIM; k0 += 32) {
        if (w != 1) stage_tile8(gsrc, A_DIM, k0, ltile, lane);
        __syncthreads();
        mfma_k32_2p(lds, wm, wn, lane, acc);
        __syncthreads();
    }

    int crow = (lane >> 4) * 4, ccol = lane & 15;
    if (MODE == 1) {
#pragma unroll
        for (int i = 0; i < 4; i++) {
            int gm = m0 + wm * 64 + i * 16 + crow;
#pragma unroll
            for (int j = 0; j < 4; j++) {
                int gn = n0 + wn * 64 + j * 16 + ccol;
#pragma unroll
                for (int r = 0; r < 4; r++) {
                    size_t idx = (size_t)(gm + r) * A_DIM + gn;
                    G[idx] = acc[i][j][r] - qt[idx];
                }
            }
        }
    } else {
        float part = 0.f;
#pragma unroll
        for (int i = 0; i < 4; i++) {
            int gm = m0 + wm * 64 + i * 16 + crow;
#pragma unroll
            for (int j = 0; j < 4; j++) {
                int gn = n0 + wn * 64 + j * 16 + ccol;
#pragma unroll
                for (int r = 0; r < 4; r++) {
                    size_t idx = (size_t)(gm + r) * A_DIM + gn;
                    float d = bf2f(Chi[idx]) + bf2f(Clo[idx]);
                    part += acc[i][j][r] * d;
                }
            }
        }
        float tot = block_reduce_sum(part, red);
        if (tid == 0) atomicAdd(scal3, tot);
    }
}

// ---------------- diff-phase small kernels ----------------

// sm = softmax(-100*g); num_cg[b] = (c-sm).g; G <- sm; Cpair <- split(sm-c)
__global__ __launch_bounds__(256) void softmax_kernel(float* __restrict__ G,
                                                      unsigned short* __restrict__ Chi,
                                                      unsigned short* __restrict__ Clo,
                                                      float* __restrict__ num_cg,
                                                      float* __restrict__ scal3) {
    __shared__ float red[256];
    int b = blockIdx.x;
    int i = threadIdx.x;
    if (b == 0 && i == 0) *scal3 = 0.f;  // reset before mfma dot dispatch
    float4* g4 = (float4*)(G + (size_t)b * A_DIM);
    ushort4* h4 = (ushort4*)(Chi + (size_t)b * A_DIM);
    ushort4* l4 = (ushort4*)(Clo + (size_t)b * A_DIM);
    float4 g = g4[i];
    ushort4 h = h4[i], l = l4[i];
    float c0 = bf2f(h.x) + bf2f(l.x);
    float c1 = bf2f(h.y) + bf2f(l.y);
    float c2 = bf2f(h.z) + bf2f(l.z);
    float c3 = bf2f(h.w) + bf2f(l.w);
    float4 t = make_float4(-TEMP_C * g.x, -TEMP_C * g.y, -TEMP_C * g.z, -TEMP_C * g.w);
    float m = fmaxf(fmaxf(t.x, t.y), fmaxf(t.z, t.w));
    float M = block_reduce_max(m, red);
    float4 e = make_float4(expf(t.x - M), expf(t.y - M), expf(t.z - M), expf(t.w - M));
    float S = block_reduce_sum(e.x + e.y + e.z + e.w, red);
    float inv = 1.f / S;
    float4 sm = make_float4(e.x * inv, e.y * inv, e.z * inv, e.w * inv);
    float np = (c0 - sm.x) * g.x + (c1 - sm.y) * g.y + (c2 - sm.z) * g.z + (c3 - sm.w) * g.w;
    g4[i] = sm;
    split2(sm.x - c0, h.x, l.x);
    split2(sm.y - c1, h.y, l.y);
    split2(sm.z - c2, h.z, l.z);
    split2(sm.w - c3, h.w, l.w);
    h4[i] = h; l4[i] = l;
    float nt = block_reduce_sum(np, red);
    if (i == 0) num_cg[b] = nt;
}

// lam = clip(num/(scal3+eps)); c' = sm - (1-lam) d  (sm in G, d in Cpair)
__global__ __launch_bounds__(256) void dupdate_kernel(const float* __restrict__ G,
                                                      unsigned short* __restrict__ Chi,
                                                      unsigned short* __restrict__ Clo,
                                                      const float* __restrict__ num_cg,
                                                      const float* __restrict__ scal3) {
    int b = blockIdx.x;
    float den = *scal3 + EPS_C;
    float lam = fminf(fmaxf(num_cg[b] / den, 0.f), 1.f);
    float om = 1.f - lam;
    int i = threadIdx.x;
    const float4* g4 = (const float4*)(G + (size_t)b * A_DIM);
    ushort4* h4 = (ushort4*)(Chi + (size_t)b * A_DIM);
    ushort4* l4 = (ushort4*)(Clo + (size_t)b * A_DIM);
    float4 sm = g4[i];
    ushort4 h = h4[i], l = l4[i];
    float d0 = bf2f(h.x) + bf2f(l.x);
    float d1 = bf2f(h.y) + bf2f(l.y);
    float d2 = bf2f(h.z) + bf2f(l.z);
    float d3 = bf2f(h.w) + bf2f(l.w);
    float c0 = sm.x - om * d0;
    float c1 = sm.y - om * d1;
    float c2 = sm.z - om * d2;
    float c3 = sm.w - om * d3;
    split2(c0, h.x, l.x);
    split2(c1, h.y, l.y);
    split2(c2, h.z, l.z);
    split2(c3, h.w, l.w);
    h4[i] = h; l4[i] = l;
}

// recon: out[b, n] = (c_b . anT[:,n]) * ynorm[b]  — pair x pair, 3 products
__global__ __launch_bounds__(256) void mfma_recon(const unsigned short* __restrict__ Chi,
                                                  const unsigned short* __restrict__ Clo,
                                                  const unsigned short* __restrict__ AnTh,
                                                  const unsigned short* __restrict__ AnTl,
                                                  const float* __restrict__ ynorm,
                                                  float* __restrict__ out) {
    __shared__ unsigned short lds[16384];
    int tid = threadIdx.x;
    int w = tid >> 6, lane = tid & 63;
    int wm = w >> 1, wn = w & 1;
    int m0 = blockIdx.y * 128, n0 = blockIdx.x * 128;

    f32x4 acc[4][4];
#pragma unroll
    for (int i = 0; i < 4; i++)
#pragma unroll
        for (int j = 0; j < 4; j++) acc[i][j] = f32x4{0.f, 0.f, 0.f, 0.f};

    const unsigned short* gsrc;
    if (w == 0) gsrc = Chi + (size_t)m0 * A_DIM;
    else if (w == 1) gsrc = Clo + (size_t)m0 * A_DIM;
    else if (w == 2) gsrc = AnTh + (size_t)n0 * A_DIM;
    else gsrc = AnTl + (size_t)n0 * A_DIM;
    unsigned short* ltile = lds + w * 4096;
    for (int k0 = 0; k0 < A_DIM; k0 += 32) {
        stage_tile8(gsrc, A_DIM, k0, ltile, lane);
        __syncthreads();
        mfma_k32(lds, wm, wn, lane, acc);
        __syncthreads();
    }

    int crow = (lane >> 4) * 4, ccol = lane & 15;
#pragma unroll
    for (int i = 0; i < 4; i++) {
        int gm = m0 + wm * 64 + i * 16 + crow;
#pragma unroll
        for (int j = 0; j < 4; j++) {
            int gn = n0 + wn * 64 + j * 16 + ccol;
#pragma unroll
            for (int r = 0; r < 4; r++)
                out[(size_t)(gm + r) * D_DIM + gn] = acc[i][j][r] * ynorm[gm + r];
        }
    }
}

// ---------------- host launch ----------------

extern "C" void kernel_launch(void* const* d_in, const int* in_sizes, int n_in,
                              void* d_out, int out_size, void* d_ws, size_t ws_size,
                              hipStream_t stream) {
    const float* y = (const float*)d_in[0];      // [B, 768]
    const float* atoms = (const float*)d_in[1];  // [A, 768]
    float* out = (float*)d_out;                  // [B, 768]

    char* ws = (char*)d_ws;
    size_t off = 0;
    auto alloc = [&](size_t bytes) -> void* {
        void* p = ws + off;
        off += (bytes + 255) & ~(size_t)255;
        return p;
    };
    const size_t BA = (size_t)B_DIM * A_DIM;
    unsigned short* Chi = (unsigned short*)alloc(BA * 2);            // 32 MiB
    unsigned short* Clo = (unsigned short*)alloc(BA * 2);            // 32 MiB
    float* Greg = (float*)alloc(BA * 4);                             // 64 MiB (aliased)
    float* qt = (float*)alloc(BA * 4);                               // 64 MiB
    unsigned short* Xhi = (unsigned short*)alloc((size_t)A_DIM * A_DIM * 2);  // 2 MiB
    unsigned short* Xlo = (unsigned short*)alloc((size_t)A_DIM * A_DIM * 2);  // 2 MiB
    float* ynorm = (float*)alloc(B_DIM * 4);
    float* anrm  = (float*)alloc(A_DIM * 4);
    float* num_cg = (float*)alloc(B_DIM * 4);
    float* num_amg = (float*)alloc(B_DIM * 4);
    unsigned long long* keysA = (unsigned long long*)alloc(A_DIM * 8);
    unsigned long long* keysB = (unsigned long long*)alloc(A_DIM * 8);
    int* bstar = (int*)alloc(A_DIM * 4);
    float* cs = (float*)alloc(A_DIM * 4);
    float* scal = (float*)alloc(256);
    (void)ws_size; (void)in_sizes; (void)n_in; (void)out_size;
    // Gregion aliases:
    float* Xf = Greg;                                  // fp32 X, 4 MiB (setup only)
    float* an = Greg + (size_t)A_DIM * A_DIM;          // an fp32, 3 MiB (setup only)
    float* G  = Greg;                                  // gradient state (nondiff+diff)
    unsigned short* AnTh = (unsigned short*)Greg;      // post-diff, 1.5 MiB
    unsigned short* AnTl = (unsigned short*)Greg + (size_t)D_DIM * A_DIM;

    // scal slots: [0]=pairs, [1]=s1 bankA, [2]=amXc, [3]=diff denom, [5]=s1 bankB
    float* scal0 = scal + 0;
    float* scal2 = scal + 2;
    float* scal3 = scal + 3;
    float* s1A = scal + 1;
    float* s1B = scal + 5;

    const dim3 ggrid(A_DIM / 128, B_DIM / 128);  // (8, 128)

    // ---- setup ----
    ynorm_kernel<<<B_DIM, 256, 0, stream>>>(y, ynorm);
    anorm_kernel<<<A_DIM, 256, 0, stream>>>(atoms, an, anrm);
    gemm_bt<0><<<dim3(A_DIM / 128, A_DIM / 128), 256, 0, stream>>>(
        an, an, nullptr, Xf, A_DIM, D_DIM);
    split_kernel<<<A_DIM * A_DIM / 4 / 256, 256, 0, stream>>>(Xf, Xhi, Xlo, A_DIM * A_DIM / 4);
    gemm_bt<3><<<dim3(A_DIM / 128, B_DIM / 128), 256, 0, stream>>>(
        y, an, ynorm, qt, A_DIM, D_DIM);
    fill_pair_kernel<<<(int)(BA / 4 / 256), 256, 0, stream>>>(Chi, Clo, BA / 4);
    colsum_kernel<<<4, 256, 0, stream>>>(Xhi, Xlo, cs);
    init_pre_kernel<<<4, 256, 0, stream>>>(keysA, keysB, scal);
    // G0 = colsum/1024 - qt (clobbers Xf/an) + initial row stats
    g0init_kernel<<<B_DIM, 256, 0, stream>>>(G, qt, cs, num_cg, s1A);
    argmin_kernel<<<dim3(A_DIM / 64, B_DIM / 1024), 256, 0, stream>>>(G, keysA);

    // ---- 30 nondiff steps (no GEMMs) ----
    for (int it = 0; it < 30; it++) {
        unsigned long long* kcur = (it & 1) ? keysB : keysA;
        unsigned long long* knxt = (it & 1) ? keysA : keysB;
        float* s1cur = (it & 1) ? s1B : s1A;
        float* s1nxt = (it & 1) ? s1A : s1B;
        initnd_kernel<<<B_DIM / 256, 256, 0, stream>>>(knxt, num_amg, scal0, scal2, s1nxt);
        statsnd_kernel<<<A_DIM, 256, 0, stream>>>(kcur, Xhi, Xlo, G, qt,
                                                  bstar, num_amg, scal0, scal2);
        fused_update<<<B_DIM, 256, 0, stream>>>(Chi, Clo, G, qt, Xhi, Xlo, bstar,
                                                num_cg, num_amg, scal0, s1cur, scal2, s1nxt);
        argmin_kernel<<<dim3(A_DIM / 64, B_DIM / 1024), 256, 0, stream>>>(G, knxt);
    }

    // ---- 10 diff steps (first one reuses G from the recurrence) ----
    for (int it = 0; it < 10; it++) {
        if (it > 0)
            gemm_single<1><<<ggrid, 256, 0, stream>>>(Chi, Xhi, Xlo, qt,
                                                      nullptr, nullptr, G, nullptr);
        softmax_kernel<<<B_DIM, 256, 0, stream>>>(G, Chi, Clo, num_cg, scal3);
        gemm_single<2><<<ggrid, 256, 0, stream>>>(Chi, Xhi, Xlo, nullptr,
                                                  Chi, Clo, nullptr, scal3);
        dupdate_kernel<<<B_DIM, 256, 0, stream>>>(G, Chi, Clo, num_cg, scal3);
    }

    // ---- recon ----
    atrans_split_kernel<<<D_DIM, 256, 0, stream>>>(atoms, anrm, AnTh, AnTl);
    mfma_recon<<<dim3(D_DIM / 128, B_DIM / 128), 256, 0, stream>>>(Chi, Clo, AnTh, AnTl,
                                                                   ynorm, out);
}

// Round 7
// 8349.279 us; speedup vs baseline: 1.5759x; 1.5759x over previous
//
#include <hip/hip_runtime.h>
#include <hip/hip_bf16.h>
#include <math.h>

// Problem constants
#define A_DIM 1024      // NB_ATOMS
#define D_DIM 768       // 3*16*16
#define B_DIM 16384     // BATCH
#define TEMP_C 100.0f
#define EPS_C 1e-8f

// Round 7 (hybrid of best-measured parts):
//  - nondiff: round-5 fused MFMA grad GEMM (bf16x2 pair-pair, argmin in epilogue)
//    with (a) XCD-slab block swizzle (each XCD owns a 16-block m-slab so Chi/Clo
//    are fetched once per XCD, X tiles stay L2-hot), (b) single qt pass in the
//    epilogue, (c) num via cxc[b]-cq[b]: per-row c.Xc accumulated in-GEMM from
//    raw acc; c.q maintained by ndupdate (which streams the row anyway).
//  - diff: round-6 structure (2-product single-A GEMMs; proven 4.88e-4).
//  - setup: qt via bf16x2 MFMA GEMM (K=768) instead of fp32 vector GEMM.
//  Workspace ~196 MiB. Greg (64 MiB) aliases: setup = Xf fp32 | an fp32 |
//  An splits | Yn splits; nondiff = Xf only (first 4 MiB); diff = G; post = AnT.

typedef __attribute__((ext_vector_type(8))) short short8;
typedef __attribute__((ext_vector_type(4))) float f32x4;
#define MFMA16(a, b, c) __builtin_amdgcn_mfma_f32_16x16x32_bf16(a, b, c, 0, 0, 0)

typedef __attribute__((address_space(3))) unsigned char lds_byte;
typedef __attribute__((address_space(1))) const unsigned char g_byte;
__device__ __forceinline__ void async_copy16(const void* gptr, void* lptr) {
    __builtin_amdgcn_global_load_lds((g_byte*)gptr, (lds_byte*)lptr, 16, 0, 0);
}

// XCD-slab swizzle for 1024-block GEMM grids (assumes dispatch ~ id%8 -> XCD):
// xcd k owns m-blocks [16k,16k+16); within a slab, n is fastest so the 128-row
// Chi/Clo slice stays hot across the 8 n-tiles.
__device__ __forceinline__ void swz(int i, int& m0, int& n0) {
    int xcd = i & 7, j = i >> 3;
    m0 = ((xcd << 4) + (j >> 3)) << 7;
    n0 = (j & 7) << 7;
}

// ---------------- small helpers ----------------

__device__ __forceinline__ float block_reduce_sum(float v, float* red) {
    int t = threadIdx.x;
    red[t] = v; __syncthreads();
    for (int off = 128; off > 0; off >>= 1) {
        if (t < off) red[t] += red[t + off];
        __syncthreads();
    }
    float r = red[0];
    __syncthreads();
    return r;
}

__device__ __forceinline__ float block_reduce_max(float v, float* red) {
    int t = threadIdx.x;
    red[t] = v; __syncthreads();
    for (int off = 128; off > 0; off >>= 1) {
        if (t < off) red[t] = fmaxf(red[t], red[t + off]);
        __syncthreads();
    }
    float r = red[0];
    __syncthreads();
    return r;
}

__device__ __forceinline__ unsigned int fkey(float v) {
    unsigned int u = __float_as_uint(v);
    return u ^ ((u & 0x80000000u) ? 0xFFFFFFFFu : 0x80000000u);
}

__device__ __forceinline__ unsigned short f2bf(float x) {
    unsigned int u = __float_as_uint(x);
    return (unsigned short)((u + 0x7FFFu + ((u >> 16) & 1u)) >> 16);
}
__device__ __forceinline__ float bf2f(unsigned short h) {
    return __uint_as_float(((unsigned int)h) << 16);
}
__device__ __forceinline__ void split2(float x, unsigned short& hi, unsigned short& lo) {
    hi = f2bf(x);
    lo = f2bf(x - bf2f(hi));
}

// ---------------- MFMA building blocks ----------------

__device__ __forceinline__ void stage_tile8(const unsigned short* gsrc, int stride, int k0,
                                            unsigned short* ltile, int lane) {
    int srow = lane >> 2;
    int scol = (lane & 3) * 8;
#pragma unroll
    for (int s = 0; s < 8; s++) {
        const unsigned short* src = gsrc + (size_t)(s * 16 + srow) * stride + k0 + scol;
        async_copy16(src, ltile + s * 512);
    }
}

// 3-product (pair x pair) K=32 step
__device__ __forceinline__ void mfma_k32(const unsigned short* lds, int wm, int wn, int lane,
                                         f32x4 acc[4][4]) {
    int frow = lane & 15, fk = (lane >> 4) * 8;
    short8 ah[4], al[4], bh[4], bl[4];
#pragma unroll
    for (int t = 0; t < 4; t++) {
        int ar = (wm * 64 + t * 16 + frow) * 32 + fk;
        ah[t] = *(const short8*)&lds[ar];
        al[t] = *(const short8*)&lds[4096 + ar];
        int br = (wn * 64 + t * 16 + frow) * 32 + fk;
        bh[t] = *(const short8*)&lds[8192 + br];
        bl[t] = *(const short8*)&lds[12288 + br];
    }
#pragma unroll
    for (int i = 0; i < 4; i++)
#pragma unroll
        for (int j = 0; j < 4; j++) {
            acc[i][j] = MFMA16(ah[i], bh[j], acc[i][j]);
            acc[i][j] = MFMA16(ah[i], bl[j], acc[i][j]);
            acc[i][j] = MFMA16(al[i], bh[j], acc[i][j]);
        }
}

// 2-product (single-A x pair-B) K=32 step
__device__ __forceinline__ void mfma_k32_2p(const unsigned short* lds, int wm, int wn, int lane,
                                            f32x4 acc[4][4]) {
    int frow = lane & 15, fk = (lane >> 4) * 8;
    short8 ah[4], bh[4], bl[4];
#pragma unroll
    for (int t = 0; t < 4; t++) {
        int ar = (wm * 64 + t * 16 + frow) * 32 + fk;
        ah[t] = *(const short8*)&lds[ar];
        int br = (wn * 64 + t * 16 + frow) * 32 + fk;
        bh[t] = *(const short8*)&lds[8192 + br];
        bl[t] = *(const short8*)&lds[12288 + br];
    }
#pragma unroll
    for (int i = 0; i < 4; i++)
#pragma unroll
        for (int j = 0; j < 4; j++) {
            acc[i][j] = MFMA16(ah[i], bh[j], acc[i][j]);
            acc[i][j] = MFMA16(ah[i], bl[j], acc[i][j]);
        }
}

// ---------------- setup kernels ----------------

__global__ __launch_bounds__(256) void ynorm_kernel(const float* __restrict__ y,
                                                    float* __restrict__ ynorm) {
    __shared__ float red[256];
    int b = blockIdx.x;
    const float* row = y + (size_t)b * D_DIM;
    float s = 0.f;
    for (int i = threadIdx.x; i < D_DIM; i += 256) s += fabsf(row[i]);
    float tot = block_reduce_sum(s, red);
    if (threadIdx.x == 0) ynorm[b] = tot;
}

// Ynh/Ynl = split(y/ynorm)
__global__ __launch_bounds__(256) void yn_split_kernel(const float* __restrict__ y,
                                                       const float* __restrict__ ynorm,
                                                       unsigned short* __restrict__ Ynh,
                                                       unsigned short* __restrict__ Ynl) {
    int b = blockIdx.x;
    float inv = 1.f / ynorm[b];
    const float* row = y + (size_t)b * D_DIM;
    unsigned short* oh = Ynh + (size_t)b * D_DIM;
    unsigned short* ol = Ynl + (size_t)b * D_DIM;
    for (int i = threadIdx.x; i < D_DIM; i += 256) {
        unsigned short h, l;
        split2(row[i] * inv, h, l);
        oh[i] = h; ol[i] = l;
    }
}

__global__ __launch_bounds__(256) void anorm_kernel(const float* __restrict__ atoms,
                                                    float* __restrict__ an,
                                                    float* __restrict__ anrm,
                                                    unsigned short* __restrict__ Anh,
                                                    unsigned short* __restrict__ Anl) {
    __shared__ float red[256];
    int a = blockIdx.x;
    const float* row = atoms + (size_t)a * D_DIM;
    float s = 0.f;
    for (int i = threadIdx.x; i < D_DIM; i += 256) s += fabsf(row[i]);
    float tot = block_reduce_sum(s, red);
    float inv = 1.f / tot;
    for (int i = threadIdx.x; i < D_DIM; i += 256) {
        float v = row[i] * inv;
        an[(size_t)a * D_DIM + i] = v;
        unsigned short h, l;
        split2(v, h, l);
        Anh[(size_t)a * D_DIM + i] = h;
        Anl[(size_t)a * D_DIM + i] = l;
    }
    if (threadIdx.x == 0) anrm[a] = tot;
}

__global__ __launch_bounds__(256) void atrans_split_kernel(const float* __restrict__ atoms,
                                                           const float* __restrict__ anrm,
                                                           unsigned short* __restrict__ AnTh,
                                                           unsigned short* __restrict__ AnTl) {
    int n = blockIdx.x;
    for (int k = threadIdx.x; k < A_DIM; k += 256) {
        float v = atoms[(size_t)k * D_DIM + n] / anrm[k];
        unsigned short h, l;
        split2(v, h, l);
        AnTh[(size_t)n * A_DIM + k] = h;
        AnTl[(size_t)n * A_DIM + k] = l;
    }
}

__global__ __launch_bounds__(256) void split_kernel(const float* __restrict__ src,
                                                    unsigned short* __restrict__ hi,
                                                    unsigned short* __restrict__ lo,
                                                    int n4) {
    int i = blockIdx.x * 256 + threadIdx.x;
    if (i < n4) {
        float4 v = ((const float4*)src)[i];
        ushort4 h, l;
        split2(v.x, h.x, l.x);
        split2(v.y, h.y, l.y);
        split2(v.z, h.z, l.z);
        split2(v.w, h.w, l.w);
        ((ushort4*)hi)[i] = h;
        ((ushort4*)lo)[i] = l;
    }
}

__global__ __launch_bounds__(256) void fill_pair_kernel(unsigned short* __restrict__ Chi,
                                                        unsigned short* __restrict__ Clo,
                                                        size_t n4) {
    size_t i = (size_t)blockIdx.x * 256 + threadIdx.x;
    if (i < n4) {
        unsigned short h, l;
        split2(1.f / A_DIM, h, l);
        ((ushort4*)Chi)[i] = make_ushort4(h, h, h, h);
        ((ushort4*)Clo)[i] = make_ushort4(l, l, l, l);
    }
}

// fp32 vector GEMM, B transposed, setup only: X = an @ an^T
__global__ __launch_bounds__(256) void gemm_xt(const float* __restrict__ Aop,
                                               float* __restrict__ Cout) {
    const int LDT = 132;
    const int N = A_DIM, K = D_DIM;
    __shared__ float As[16 * LDT];
    __shared__ float Bs[16 * LDT];
    int m0 = blockIdx.y * 128, n0 = blockIdx.x * 128;
    int tid = threadIdx.x;
    int tx = tid & 15, ty = tid >> 4;
    float acc[8][8];
#pragma unroll
    for (int i = 0; i < 8; i++)
#pragma unroll
        for (int j = 0; j < 8; j++) acc[i][j] = 0.f;
    for (int k0 = 0; k0 < K; k0 += 16) {
#pragma unroll
        for (int s = 0; s < 2; s++) {
            int idx = tid + s * 256;
            int row = idx >> 2, kq = (idx & 3) * 4;
            float4 v = *(const float4*)(Aop + (size_t)(m0 + row) * K + k0 + kq);
            As[(kq + 0) * LDT + row] = v.x;
            As[(kq + 1) * LDT + row] = v.y;
            As[(kq + 2) * LDT + row] = v.z;
            As[(kq + 3) * LDT + row] = v.w;
        }
#pragma unroll
        for (int s = 0; s < 2; s++) {
            int idx = tid + s * 256;
            int row = idx >> 2, kq = (idx & 3) * 4;
            float4 v = *(const float4*)(Aop + (size_t)(n0 + row) * K + k0 + kq);
            Bs[(kq + 0) * LDT + row] = v.x;
            Bs[(kq + 1) * LDT + row] = v.y;
            Bs[(kq + 2) * LDT + row] = v.z;
            Bs[(kq + 3) * LDT + row] = v.w;
        }
        __syncthreads();
#pragma unroll
        for (int kk = 0; kk < 16; kk++) {
            float a[8], b[8];
            *(float4*)(a)     = *(const float4*)(As + kk * LDT + ty * 8);
            *(float4*)(a + 4) = *(const float4*)(As + kk * LDT + ty * 8 + 4);
            *(float4*)(b)     = *(const float4*)(Bs + kk * LDT + tx * 8);
            *(float4*)(b + 4) = *(const float4*)(Bs + kk * LDT + tx * 8 + 4);
#pragma unroll
            for (int i = 0; i < 8; i++)
#pragma unroll
                for (int j = 0; j < 8; j++) acc[i][j] = fmaf(a[i], b[j], acc[i][j]);
        }
        __syncthreads();
    }
#pragma unroll
    for (int i = 0; i < 8; i++) {
        int row = m0 + ty * 8 + i;
#pragma unroll
        for (int j = 0; j < 8; j += 4) {
            int col = n0 + tx * 8 + j;
            float4 v = make_float4(acc[i][j], acc[i][j + 1], acc[i][j + 2], acc[i][j + 3]);
            *(float4*)(Cout + (size_t)row * N + col) = v;
        }
    }
}

// qt = Yn @ An^T  (bf16x2 pair-pair MFMA, K=768), swizzled 1D grid of 1024
__global__ __launch_bounds__(256) void qt_mfma(const unsigned short* __restrict__ Ynh,
                                               const unsigned short* __restrict__ Ynl,
                                               const unsigned short* __restrict__ Anh,
                                               const unsigned short* __restrict__ Anl,
                                               float* __restrict__ qt) {
    __shared__ unsigned short lds[16384];
    int tid = threadIdx.x;
    int w = tid >> 6, lane = tid & 63;
    int wm = w >> 1, wn = w & 1;
    int m0, n0;
    swz(blockIdx.x, m0, n0);

    f32x4 acc[4][4];
#pragma unroll
    for (int i = 0; i < 4; i++)
#pragma unroll
        for (int j = 0; j < 4; j++) acc[i][j] = f32x4{0.f, 0.f, 0.f, 0.f};

    const unsigned short* gsrc;
    if (w == 0) gsrc = Ynh + (size_t)m0 * D_DIM;
    else if (w == 1) gsrc = Ynl + (size_t)m0 * D_DIM;
    else if (w == 2) gsrc = Anh + (size_t)n0 * D_DIM;
    else gsrc = Anl + (size_t)n0 * D_DIM;
    unsigned short* ltile = lds + w * 4096;
    for (int k0 = 0; k0 < D_DIM; k0 += 32) {
        stage_tile8(gsrc, D_DIM, k0, ltile, lane);
        __syncthreads();
        mfma_k32(lds, wm, wn, lane, acc);
        __syncthreads();
    }

    int crow = (lane >> 4) * 4, ccol = lane & 15;
#pragma unroll
    for (int i = 0; i < 4; i++) {
        int gm = m0 + wm * 64 + i * 16 + crow;
#pragma unroll
        for (int j = 0; j < 4; j++) {
            int gn = n0 + wn * 64 + j * 16 + ccol;
#pragma unroll
            for (int r = 0; r < 4; r++)
                qt[(size_t)(gm + r) * A_DIM + gn] = acc[i][j][r];
        }
    }
}

// cq0[b] = sum_a qt[b,a] / 1024  (initial c.q for uniform c)
__global__ __launch_bounds__(256) void cq0_kernel(const float* __restrict__ qt,
                                                  float* __restrict__ cq) {
    __shared__ float red[256];
    int b = blockIdx.x;
    float4 q = ((const float4*)(qt + (size_t)b * A_DIM))[threadIdx.x];
    float s = (q.x + q.y + q.z + q.w) * (1.f / A_DIM);
    float t = block_reduce_sum(s, red);
    if (threadIdx.x == 0) cq[b] = t;
}

// ---------------- nondiff per-iteration kernels ----------------

// zero keys / num_amg / cxc / scal
__global__ __launch_bounds__(256) void init_kernel(unsigned long long* __restrict__ keys,
                                                   float* __restrict__ num_amg,
                                                   float* __restrict__ cxc,
                                                   float* __restrict__ scal) {
    int i = blockIdx.x * 256 + threadIdx.x;
    num_amg[i] = 0.f;
    cxc[i] = 0.f;
    if (i < A_DIM) keys[i] = ~0ULL;
    if (i < 4) scal[i] = 0.f;
}

// nondiff fused GEMM: acc = split(c)@split(X) (K=1024, 3 products).
// Epilogue: per-row c.(Xc) partials -> cxc[b] (raw acc, needs c tile reads);
// column argmin of g = acc - qt (single qt pass) -> keys.
__global__ __launch_bounds__(256) void fused_grad(const unsigned short* __restrict__ Chi,
                                                  const unsigned short* __restrict__ Clo,
                                                  const unsigned short* __restrict__ Xhi,
                                                  const unsigned short* __restrict__ Xlo,
                                                  const float* __restrict__ qt,
                                                  unsigned long long* __restrict__ keys,
                                                  float* __restrict__ cxc) {
    __shared__ unsigned short lds[16384];
    int tid = threadIdx.x;
    int w = tid >> 6, lane = tid & 63;
    int wm = w >> 1, wn = w & 1;
    int m0, n0;
    swz(blockIdx.x, m0, n0);

    f32x4 acc[4][4];
#pragma unroll
    for (int i = 0; i < 4; i++)
#pragma unroll
        for (int j = 0; j < 4; j++) acc[i][j] = f32x4{0.f, 0.f, 0.f, 0.f};

    const unsigned short* gsrc;
    if (w == 0) gsrc = Chi + (size_t)m0 * A_DIM;
    else if (w == 1) gsrc = Clo + (size_t)m0 * A_DIM;
    else if (w == 2) gsrc = Xhi + (size_t)n0 * A_DIM;
    else gsrc = Xlo + (size_t)n0 * A_DIM;
    unsigned short* ltile = lds + w * 4096;
    for (int k0 = 0; k0 < A_DIM; k0 += 32) {
        stage_tile8(gsrc, A_DIM, k0, ltile, lane);
        __syncthreads();
        mfma_k32(lds, wm, wn, lane, acc);
        __syncthreads();
    }

    int crow = (lane >> 4) * 4, ccol = lane & 15;

    // per-row c.(Xc) partials from RAW acc (Xc = acc)
#pragma unroll
    for (int i = 0; i < 4; i++)
#pragma unroll
        for (int r = 0; r < 4; r++) {
            int gm = m0 + wm * 64 + i * 16 + crow + r;
            float pcx = 0.f;
#pragma unroll
            for (int j = 0; j < 4; j++) {
                int gn = n0 + wn * 64 + j * 16 + ccol;
                size_t idx = (size_t)gm * A_DIM + gn;
                float c = bf2f(Chi[idx]) + bf2f(Clo[idx]);
                pcx += c * acc[i][j][r];
            }
            for (int mm = 1; mm < 16; mm <<= 1) pcx += __shfl_xor(pcx, mm, 16);
            if (ccol == 0) atomicAdd(&cxc[gm], pcx);
        }

    // column argmin of g = acc - qt (single qt pass)
#pragma unroll
    for (int j = 0; j < 4; j++) {
        int gn = n0 + wn * 64 + j * 16 + ccol;
        unsigned long long best = ~0ULL;
#pragma unroll
        for (int i = 0; i < 4; i++)
#pragma unroll
            for (int r = 0; r < 4; r++) {
                int b = m0 + wm * 64 + i * 16 + crow + r;
                float g = acc[i][j][r] - qt[(size_t)b * A_DIM + gn];
                unsigned long long key =
                    ((unsigned long long)fkey(g) << 32) | (unsigned int)b;
                if (key < best) best = key;
            }
        unsigned long long o = __shfl_xor(best, 16);
        if (o < best) best = o;
        o = __shfl_xor(best, 32);
        if (o < best) best = o;
        if ((lane >> 4) == 0) atomicMin(&keys[gn], best);
    }
}

// merged stats. Block per atom a:
//   ba = keys[a].low; bstar[a] = ba
//   scal0 += sum_{i: keys[i].low==ba} Xf[a,i]          (pairs)
//   xc = Xf[a,:] . c[ba,:] (fp32-exact);  scal2 += xc; num_amg[ba] += xc - qt[ba,a]
//   scal1 += sum of cxc[16a .. 16a+16)                 (Sum_b c.Xc)
__global__ __launch_bounds__(256) void stats_kernel(const float* __restrict__ Xf,
                                                    const unsigned long long* __restrict__ keys,
                                                    const unsigned short* __restrict__ Chi,
                                                    const unsigned short* __restrict__ Clo,
                                                    const float* __restrict__ qt,
                                                    const float* __restrict__ cxc,
                                                    int* __restrict__ bstar,
                                                    float* __restrict__ num_amg,
                                                    float* __restrict__ scal) {
    __shared__ float red[256];
    int a = blockIdx.x;
    int ba = (int)(unsigned int)(keys[a] & 0xFFFFFFFFULL);
    const float* xr = Xf + (size_t)a * A_DIM;
    const unsigned short* ch = Chi + (size_t)ba * A_DIM;
    const unsigned short* cl = Clo + (size_t)ba * A_DIM;
    float ps = 0.f, xs = 0.f;
    for (int i = threadIdx.x; i < A_DIM; i += 256) {
        float xv = xr[i];
        if ((int)(unsigned int)(keys[i] & 0xFFFFFFFFULL) == ba) ps += xv;
        xs += xv * (bf2f(ch[i]) + bf2f(cl[i]));
    }
    float s1p = (threadIdx.x < 16) ? cxc[(a << 4) + threadIdx.x] : 0.f;
    float pt = block_reduce_sum(ps, red);
    float xc = block_reduce_sum(xs, red);
    float s1 = block_reduce_sum(s1p, red);
    if (threadIdx.x == 0) {
        bstar[a] = ba;
        atomicAdd(&scal[0], pt);
        atomicAdd(&scal[2], xc);
        atomicAdd(&scal[1], s1);
        atomicAdd(&num_amg[ba], xc - qt[(size_t)ba * A_DIM + a]);
    }
}

// nondiff update: lam = clip((cxc-cq-amg)/(scal0+scal1-2*scal2+eps));
// c' = (1-lam)c + lam*am; refresh splits; cq[b] <- c'.q  (for next iter)
__global__ __launch_bounds__(256) void ndupdate_kernel(unsigned short* __restrict__ Chi,
                                                       unsigned short* __restrict__ Clo,
                                                       const int* __restrict__ bstar,
                                                       const float* __restrict__ qt,
                                                       const float* __restrict__ cxc,
                                                       float* __restrict__ cq,
                                                       const float* __restrict__ num_amg,
                                                       const float* __restrict__ scal) {
    __shared__ float red[256];
    int b = blockIdx.x;
    float den = scal[0] + scal[1] - 2.f * scal[2] + EPS_C;
    float lam = fminf(fmaxf((cxc[b] - cq[b] - num_amg[b]) / den, 0.f), 1.f);
    float om = 1.f - lam;
    int i = threadIdx.x;
    ushort4* h4 = (ushort4*)(Chi + (size_t)b * A_DIM);
    ushort4* l4 = (ushort4*)(Clo + (size_t)b * A_DIM);
    ushort4 h = h4[i], l = l4[i];
    int4 bs = ((const int4*)bstar)[i];
    float4 q = ((const float4*)(qt + (size_t)b * A_DIM))[i];
    float c0 = om * (bf2f(h.x) + bf2f(l.x)) + lam * ((bs.x == b) ? 1.f : 0.f);
    float c1 = om * (bf2f(h.y) + bf2f(l.y)) + lam * ((bs.y == b) ? 1.f : 0.f);
    float c2 = om * (bf2f(h.z) + bf2f(l.z)) + lam * ((bs.z == b) ? 1.f : 0.f);
    float c3 = om * (bf2f(h.w) + bf2f(l.w)) + lam * ((bs.w == b) ? 1.f : 0.f);
    split2(c0, h.x, l.x);
    split2(c1, h.y, l.y);
    split2(c2, h.z, l.z);
    split2(c3, h.w, l.w);
    h4[i] = h; l4[i] = l;
    float s = c0 * q.x + c1 * q.y + c2 * q.z + c3 * q.w;
    float t = block_reduce_sum(s, red);
    if (i == 0) cq[b] = t;
}

// ---------------- diff-phase GEMM (single-A x pair-X, 2 products) ----------------
// MODE 1: G[idx] = acc - qt[idx]            (A = c-hi)
// MODE 2: scal3 += sum(acc * recon(Chi,Clo))(A = d-hi, dot for denominator)
template <int MODE>
__global__ __launch_bounds__(256) void gemm_single(const unsigned short* __restrict__ Ahi,
                                                   const unsigned short* __restrict__ Xhi,
                                                   const unsigned short* __restrict__ Xlo,
                                                   const float* __restrict__ qt,
                                                   const unsigned short* __restrict__ Chi,
                                                   const unsigned short* __restrict__ Clo,
                                                   float* __restrict__ G,
                                                   float* __restrict__ scal3) {
    __shared__ unsigned short lds[16384];
    __shared__ float red[256];
    int tid = threadIdx.x;
    int w = tid >> 6, lane = tid & 63;
    int wm = w >> 1, wn = w & 1;
    int m0, n0;
    swz(blockIdx.x, m0, n0);

    f32x4 acc[4][4];
#pragma unroll
    for (int i = 0; i < 4; i++)
#pragma unroll
        for (int j = 0; j < 4; j++) acc[i][j] = f32x4{0.f, 0.f, 0.f, 0.f};

    const unsigned short* gsrc = nullptr;
    unsigned short* ltile = nullptr;
    if (w == 0) { gsrc = Ahi + (size_t)m0 * A_DIM; ltile = lds; }
    else if (w == 2) { gsrc = Xhi + (size_t)n0 * A_DIM; ltile = lds + 8192; }
    else if (w == 3) { gsrc = Xlo + (size_t)n0 * A_DIM; ltile = lds + 12288; }
    for (int k0 = 0; k0 < A_DIM; k0 += 32) {
        if (w != 1) stage_tile8(gsrc, A_DIM, k0, ltile, lane);
        __syncthreads();
        mfma_k32_2p(lds, wm, wn, lane, acc);
        __syncthreads();
    }

    int crow = (lane >> 4) * 4, ccol = lane & 15;
    if (MODE == 1) {
#pragma unroll
        for (int i = 0; i < 4; i++) {
            int gm = m0 + wm * 64 + i * 16 + crow;
#pragma unroll
            for (int j = 0; j < 4; j++) {
                int gn = n0 + wn * 64 + j * 16 + ccol;
#pragma unroll
                for (int r = 0; r < 4; r++) {
                    size_t idx = (size_t)(gm + r) * A_DIM + gn;
                    G[idx] = acc[i][j][r] - qt[idx];
                }
            }
        }
    } else {
        float part = 0.f;
#pragma unroll
        for (int i = 0; i < 4; i++) {
            int gm = m0 + wm * 64 + i * 16 + crow;
#pragma unroll
            for (int j = 0; j < 4; j++) {
                int gn = n0 + wn * 64 + j * 16 + ccol;
#pragma unroll
                for (int r = 0; r < 4; r++) {
                    size_t idx = (size_t)(gm + r) * A_DIM + gn;
                    float d = bf2f(Chi[idx]) + bf2f(Clo[idx]);
                    part += acc[i][j][r] * d;
                }
            }
        }
        float tot = block_reduce_sum(part, red);
        if (tid == 0) atomicAdd(scal3, tot);
    }
}

// ---------------- diff-phase small kernels ----------------

__global__ __launch_bounds__(256) void softmax_kernel(float* __restrict__ G,
                                                      unsigned short* __restrict__ Chi,
                                                      unsigned short* __restrict__ Clo,
                                                      float* __restrict__ num_cg,
                                                      float* __restrict__ scal3) {
    __shared__ float red[256];
    int b = blockIdx.x;
    int i = threadIdx.x;
    if (b == 0 && i == 0) *scal3 = 0.f;  // reset before the dot dispatch
    float4* g4 = (float4*)(G + (size_t)b * A_DIM);
    ushort4* h4 = (ushort4*)(Chi + (size_t)b * A_DIM);
    ushort4* l4 = (ushort4*)(Clo + (size_t)b * A_DIM);
    float4 g = g4[i];
    ushort4 h = h4[i], l = l4[i];
    float c0 = bf2f(h.x) + bf2f(l.x);
    float c1 = bf2f(h.y) + bf2f(l.y);
    float c2 = bf2f(h.z) + bf2f(l.z);
    float c3 = bf2f(h.w) + bf2f(l.w);
    float4 t = make_float4(-TEMP_C * g.x, -TEMP_C * g.y, -TEMP_C * g.z, -TEMP_C * g.w);
    float m = fmaxf(fmaxf(t.x, t.y), fmaxf(t.z, t.w));
    float M = block_reduce_max(m, red);
    float4 e = make_float4(expf(t.x - M), expf(t.y - M), expf(t.z - M), expf(t.w - M));
    float S = block_reduce_sum(e.x + e.y + e.z + e.w, red);
    float inv = 1.f / S;
    float4 sm = make_float4(e.x * inv, e.y * inv, e.z * inv, e.w * inv);
    float np = (c0 - sm.x) * g.x + (c1 - sm.y) * g.y + (c2 - sm.z) * g.z + (c3 - sm.w) * g.w;
    g4[i] = sm;
    split2(sm.x - c0, h.x, l.x);
    split2(sm.y - c1, h.y, l.y);
    split2(sm.z - c2, h.z, l.z);
    split2(sm.w - c3, h.w, l.w);
    h4[i] = h; l4[i] = l;
    float nt = block_reduce_sum(np, red);
    if (i == 0) num_cg[b] = nt;
}

__global__ __launch_bounds__(256) void dupdate_kernel(const float* __restrict__ G,
                                                      unsigned short* __restrict__ Chi,
                                                      unsigned short* __restrict__ Clo,
                                                      const float* __restrict__ num_cg,
                                                      const float* __restrict__ scal3) {
    int b = blockIdx.x;
    float den = *scal3 + EPS_C;
    float lam = fminf(fmaxf(num_cg[b] / den, 0.f), 1.f);
    float om = 1.f - lam;
    int i = threadIdx.x;
    const float4* g4 = (const float4*)(G + (size_t)b * A_DIM);
    ushort4* h4 = (ushort4*)(Chi + (size_t)b * A_DIM);
    ushort4* l4 = (ushort4*)(Clo + (size_t)b * A_DIM);
    float4 sm = g4[i];
    ushort4 h = h4[i], l = l4[i];
    float c0 = sm.x - om * (bf2f(h.x) + bf2f(l.x));
    float c1 = sm.y - om * (bf2f(h.y) + bf2f(l.y));
    float c2 = sm.z - om * (bf2f(h.z) + bf2f(l.z));
    float c3 = sm.w - om * (bf2f(h.w) + bf2f(l.w));
    split2(c0, h.x, l.x);
    split2(c1, h.y, l.y);
    split2(c2, h.z, l.z);
    split2(c3, h.w, l.w);
    h4[i] = h; l4[i] = l;
}

// recon: out[b, n] = (c_b . anT[:,n]) * ynorm[b]
__global__ __launch_bounds__(256) void mfma_recon(const unsigned short* __restrict__ Chi,
                                                  const unsigned short* __restrict__ Clo,
                                                  const unsigned short* __restrict__ AnTh,
                                                  const unsigned short* __restrict__ AnTl,
                                                  const float* __restrict__ ynorm,
                                                  float* __restrict__ out) {
    __shared__ unsigned short lds[16384];
    int tid = threadIdx.x;
    int w = tid >> 6, lane = tid & 63;
    int wm = w >> 1, wn = w & 1;
    int m0 = blockIdx.y * 128, n0 = blockIdx.x * 128;

    f32x4 acc[4][4];
#pragma unroll
    for (int i = 0; i < 4; i++)
#pragma unroll
        for (int j = 0; j < 4; j++) acc[i][j] = f32x4{0.f, 0.f, 0.f, 0.f};

    const unsigned short* gsrc;
    if (w == 0) gsrc = Chi + (size_t)m0 * A_DIM;
    else if (w == 1) gsrc = Clo + (size_t)m0 * A_DIM;
    else if (w == 2) gsrc = AnTh + (size_t)n0 * A_DIM;
    else gsrc = AnTl + (size_t)n0 * A_DIM;
    unsigned short* ltile = lds + w * 4096;
    for (int k0 = 0; k0 < A_DIM; k0 += 32) {
        stage_tile8(gsrc, A_DIM, k0, ltile, lane);
        __syncthreads();
        mfma_k32(lds, wm, wn, lane, acc);
        __syncthreads();
    }

    int crow = (lane >> 4) * 4, ccol = lane & 15;
#pragma unroll
    for (int i = 0; i < 4; i++) {
        int gm = m0 + wm * 64 + i * 16 + crow;
#pragma unroll
        for (int j = 0; j < 4; j++) {
            int gn = n0 + wn * 64 + j * 16 + ccol;
#pragma unroll
            for (int r = 0; r < 4; r++)
                out[(size_t)(gm + r) * D_DIM + gn] = acc[i][j][r] * ynorm[gm + r];
        }
    }
}

// ---------------- host launch ----------------

extern "C" void kernel_launch(void* const* d_in, const int* in_sizes, int n_in,
                              void* d_out, int out_size, void* d_ws, size_t ws_size,
                              hipStream_t stream) {
    const float* y = (const float*)d_in[0];      // [B, 768]
    const float* atoms = (const float*)d_in[1];  // [A, 768]
    float* out = (float*)d_out;                  // [B, 768]

    char* ws = (char*)d_ws;
    size_t off = 0;
    auto alloc = [&](size_t bytes) -> void* {
        void* p = ws + off;
        off += (bytes + 255) & ~(size_t)255;
        return p;
    };
    const size_t BA = (size_t)B_DIM * A_DIM;
    unsigned short* Chi = (unsigned short*)alloc(BA * 2);            // 32 MiB
    unsigned short* Clo = (unsigned short*)alloc(BA * 2);            // 32 MiB
    float* Greg = (float*)alloc(BA * 4);                             // 64 MiB (aliased)
    float* qt = (float*)alloc(BA * 4);                               // 64 MiB
    unsigned short* Xhi = (unsigned short*)alloc((size_t)A_DIM * A_DIM * 2);  // 2 MiB
    unsigned short* Xlo = (unsigned short*)alloc((size_t)A_DIM * A_DIM * 2);  // 2 MiB
    float* ynorm = (float*)alloc(B_DIM * 4);
    float* anrm  = (float*)alloc(A_DIM * 4);
    float* cxc   = (float*)alloc(B_DIM * 4);
    float* cq    = (float*)alloc(B_DIM * 4);
    float* num_amg = (float*)alloc(B_DIM * 4);
    float* num_cg  = (float*)alloc(B_DIM * 4);
    unsigned long long* keys = (unsigned long long*)alloc(A_DIM * 8);
    int* bstar = (int*)alloc(A_DIM * 4);
    float* scal = (float*)alloc(256);
    (void)ws_size; (void)in_sizes; (void)n_in; (void)out_size;

    // Greg aliases (floats):
    float* Xf = Greg;                                         // 4 MiB, live thru nondiff
    float* an = Greg + (size_t)A_DIM * A_DIM;                 // 3 MiB, setup only
    unsigned short* Anh = (unsigned short*)(an + (size_t)A_DIM * D_DIM);          // 1.5 MiB
    unsigned short* Anl = Anh + (size_t)A_DIM * D_DIM;                            // 1.5 MiB
    unsigned short* Ynh = Anl + (size_t)A_DIM * D_DIM;                            // 24 MiB
    unsigned short* Ynl = Ynh + (size_t)B_DIM * D_DIM;                            // 24 MiB
    float* G = Greg;                                          // diff phase (clobbers all)
    unsigned short* AnTh = (unsigned short*)Greg;             // post-diff recon
    unsigned short* AnTl = (unsigned short*)Greg + (size_t)D_DIM * A_DIM;

    // ---- setup ----
    ynorm_kernel<<<B_DIM, 256, 0, stream>>>(y, ynorm);
    yn_split_kernel<<<B_DIM, 256, 0, stream>>>(y, ynorm, Ynh, Ynl);
    anorm_kernel<<<A_DIM, 256, 0, stream>>>(atoms, an, anrm, Anh, Anl);
    gemm_xt<<<dim3(A_DIM / 128, A_DIM / 128), 256, 0, stream>>>(an, Xf);
    split_kernel<<<A_DIM * A_DIM / 4 / 256, 256, 0, stream>>>(Xf, Xhi, Xlo, A_DIM * A_DIM / 4);
    qt_mfma<<<1024, 256, 0, stream>>>(Ynh, Ynl, Anh, Anl, qt);
    fill_pair_kernel<<<(int)(BA / 4 / 256), 256, 0, stream>>>(Chi, Clo, BA / 4);
    cq0_kernel<<<B_DIM, 256, 0, stream>>>(qt, cq);

    // ---- 30 nondiff steps ----
    for (int it = 0; it < 30; it++) {
        init_kernel<<<B_DIM / 256, 256, 0, stream>>>(keys, num_amg, cxc, scal);
        fused_grad<<<1024, 256, 0, stream>>>(Chi, Clo, Xhi, Xlo, qt, keys, cxc);
        stats_kernel<<<A_DIM, 256, 0, stream>>>(Xf, keys, Chi, Clo, qt, cxc,
                                                bstar, num_amg, scal);
        ndupdate_kernel<<<B_DIM, 256, 0, stream>>>(Chi, Clo, bstar, qt, cxc, cq,
                                                   num_amg, scal);
    }

    // ---- 10 diff steps (G clobbers Xf/setup region) ----
    for (int it = 0; it < 10; it++) {
        gemm_single<1><<<1024, 256, 0, stream>>>(Chi, Xhi, Xlo, qt,
                                                 nullptr, nullptr, G, nullptr);
        softmax_kernel<<<B_DIM, 256, 0, stream>>>(G, Chi, Clo, num_cg, &scal[3]);
        gemm_single<2><<<1024, 256, 0, stream>>>(Chi, Xhi, Xlo, nullptr,
                                                 Chi, Clo, nullptr, &scal[3]);
        dupdate_kernel<<<B_DIM, 256, 0, stream>>>(G, Chi, Clo, num_cg, &scal[3]);
    }

    // ---- recon ----
    atrans_split_kernel<<<D_DIM, 256, 0, stream>>>(atoms, anrm, AnTh, AnTl);
    mfma_recon<<<dim3(D_DIM / 128, B_DIM / 128), 256, 0, stream>>>(Chi, Clo, AnTh, AnTl,
                                                                   ynorm, out);
}